// Round 5
// baseline (138.511 us; speedup 1.0000x reference)
//
#include <hip/hip_runtime.h>
#include <hip/hip_bf16.h>

#define N_ROWS 4096
#define TWO_N 8192
#define DIM 512
#define BK 32
#define NKS (DIM / BK)                      // 16 K-steps
#define INV_T 14.285714285714286f           // 1/0.07
#define LOG2E 1.4426950408889634f
#define C_LOG2E 20.60992915555662f          // (1/0.07)*log2(e)
#define INV_SQRT_T 3.7796447300922722f      // 1/sqrt(0.07)

typedef __bf16 bf16x8 __attribute__((ext_vector_type(8)));
typedef float f32x4 __attribute__((ext_vector_type(4)));

#define ASYNC_COPY16(gp, lp)                                                     \
  __builtin_amdgcn_global_load_lds((const __attribute__((address_space(1))) void*)(gp), \
                                   (__attribute__((address_space(3))) void*)(lp), 16, 0, 0)

#define VMCNT(n) asm volatile("s_waitcnt vmcnt(" #n ")" ::: "memory")

// Wave-per-row prep: float4 loads, butterfly shuffle reduce (no LDS/sync),
// 16B bf16x8 stores. 1024 blocks x 4 waves = 4096 rows; also zeroes rowsum.
__global__ __launch_bounds__(256) void k_prep(const float* __restrict__ z1,
                                              const float* __restrict__ z2,
                                              __hip_bfloat16* __restrict__ zn,
                                              float* __restrict__ posbuf,
                                              float* __restrict__ rowsum) {
  const int t = threadIdx.x;
  const int wv = t >> 6, lane = t & 63;
  const int r = blockIdx.x * 4 + wv;
  if (blockIdx.x < 32) rowsum[blockIdx.x * 256 + t] = 0.f;   // 32*256 = 8192

  const float4* p1 = reinterpret_cast<const float4*>(z1 + (size_t)r * DIM) + (lane << 1);
  const float4* p2 = reinterpret_cast<const float4*>(z2 + (size_t)r * DIM) + (lane << 1);
  float4 a0 = p1[0], a1 = p1[1];
  float4 b0 = p2[0], b1 = p2[1];

  float s1 = a0.x * a0.x + a0.y * a0.y + a0.z * a0.z + a0.w * a0.w
           + a1.x * a1.x + a1.y * a1.y + a1.z * a1.z + a1.w * a1.w;
  float s2 = b0.x * b0.x + b0.y * b0.y + b0.z * b0.z + b0.w * b0.w
           + b1.x * b1.x + b1.y * b1.y + b1.z * b1.z + b1.w * b1.w;
  float sd = a0.x * b0.x + a0.y * b0.y + a0.z * b0.z + a0.w * b0.w
           + a1.x * b1.x + a1.y * b1.y + a1.z * b1.z + a1.w * b1.w;
#pragma unroll
  for (int off = 1; off < 64; off <<= 1) {
    s1 += __shfl_xor(s1, off, 64);
    s2 += __shfl_xor(s2, off, 64);
    sd += __shfl_xor(sd, off, 64);
  }
  const float sc1 = INV_SQRT_T / fmaxf(sqrtf(s1), 1e-8f);
  const float sc2 = INV_SQRT_T / fmaxf(sqrtf(s2), 1e-8f);

  bf16x8 o;
  o[0] = (__bf16)(a0.x * sc1); o[1] = (__bf16)(a0.y * sc1);
  o[2] = (__bf16)(a0.z * sc1); o[3] = (__bf16)(a0.w * sc1);
  o[4] = (__bf16)(a1.x * sc1); o[5] = (__bf16)(a1.y * sc1);
  o[6] = (__bf16)(a1.z * sc1); o[7] = (__bf16)(a1.w * sc1);
  *reinterpret_cast<bf16x8*>(zn + (size_t)r * DIM + (lane << 3)) = o;

  o[0] = (__bf16)(b0.x * sc2); o[1] = (__bf16)(b0.y * sc2);
  o[2] = (__bf16)(b0.z * sc2); o[3] = (__bf16)(b0.w * sc2);
  o[4] = (__bf16)(b1.x * sc2); o[5] = (__bf16)(b1.y * sc2);
  o[6] = (__bf16)(b1.z * sc2); o[7] = (__bf16)(b1.w * sc2);
  *reinterpret_cast<bf16x8*>(zn + (size_t)(r + N_ROWS) * DIM + (lane << 3)) = o;

  if (lane == 0) posbuf[r] = sd * sc1 * sc2;   // = cos(z1_r,z2_r)/T
}

// ---------------------------------------------------------------------------
// Flash-LSE GEMM over upper-triangle 128x128 tiles, "minimum 2-phase" loop:
//   STAGE(buf^1, t+1) -> ds_read(buf) -> 16 MFMA -> vmcnt(0) -> s_barrier
// Only 2 LDS buffers (32 KB total) -> 4 blocks/CU (launch_bounds(256,4)),
// 16 waves/CU. Rationale (r4 post-mortem): a barrier per K-step phase-locks
// all waves of a block (all ds_read together, then all MFMA together -> pipes
// alternate at ~20% each). Cross-BLOCK stagger is what provides overlap, so
// maximize independent resident blocks (r2 had 3; r4's 2 made it worse) and
// keep per-block iterations short. The vmcnt(0) here is cheap: the staged
// loads were issued BEFORE the reads+MFMA (~400+ cy earlier), unlike r1's
// post-barrier issue which drained ~300cy-old loads every iteration.
// Buffer safety: iter t stages into buf[cur^1], last read at iter t-1 and
// protected by iter t-1's end barrier; end-of-iter vmcnt(0)+barrier ensures
// every wave's stage landed before anyone reads it next iter.
//
// LDS swizzle (r4-proven, 0 bank conflicts): 16B granule of logical (row,g)
// stored at slot row*4 + (g ^ ((row>>1)&3)). Store side keeps the LDS dest
// linear (slot = tid + 256c, rule #21) and pre-swizzles the GLOBAL source
// granule kg0 = (tid&3)^((tid>>3)&3); ds_read applies the same XOR
// (kxl = (q ^ ((cl>>1)&3))<<4) -> each 16-lane batch covers all 8 bank
// quads, 2 lanes each (2-way is free).
// ---------------------------------------------------------------------------
__global__ __launch_bounds__(256, 4) void k_lse(const __hip_bfloat16* __restrict__ Zn,
                                                float* __restrict__ rowsum) {
  __shared__ char smem[32768] __attribute__((aligned(16)));
  const int tid  = threadIdx.x;
  const int wave = tid >> 6;
  const int lane = tid & 63;
  const int cl   = lane & 15;
  const int q    = lane >> 4;

  // XCD-aware bijective swizzle: 2080 = 8 * 260.
  const int b = (blockIdx.x & 7) * 260 + (blockIdx.x >> 3);

  // linear tile -> (rt, ct) with rt <= ct over 64x64 tile grid
  int rt = (int)((129.0f - sqrtf(16641.0f - 8.0f * (float)b)) * 0.5f);
  if (rt > 63) rt = 63;
  if (rt < 0) rt = 0;
  while (rt > 0 && 64 * rt - rt * (rt - 1) / 2 > b) rt--;
  while (64 * (rt + 1) - (rt + 1) * rt / 2 <= b) rt++;
  const int ct = rt + (b - (64 * rt - rt * (rt - 1) / 2));

  const int wr = (wave >> 1) * 64;   // wave's row offset in tile
  const int wc = (wave & 1) * 64;    // wave's col offset in tile

  // staging: thread owns slots tid, tid+256 of each 128x32 tile (512 granules)
  const int r0  = tid >> 2;                         // 0..63
  const int kg0 = (tid & 3) ^ ((tid >> 3) & 3);     // pre-swizzled granule
  const __hip_bfloat16* gA0 = Zn + (size_t)(rt * 128 + r0) * DIM + kg0 * 8;
  const __hip_bfloat16* gB0 = Zn + (size_t)(ct * 128 + r0) * DIM + kg0 * 8;

  f32x4 acc[4][4] = {};
  // fragment-read byte offset within a row: same XOR as the store side
  const int kxl = (q ^ ((cl >> 1) & 3)) << 4;

#define STAGE(d, ks1)                                                       \
  {                                                                         \
    char* _b = smem + (d) * 16384 + wave * 1024;                            \
    const int _ko = (ks1) * BK;                                             \
    ASYNC_COPY16(gA0 + _ko,            _b);                                 \
    ASYNC_COPY16(gA0 + _ko + 64 * DIM, _b + 4096);                          \
    ASYNC_COPY16(gB0 + _ko,            _b + 8192);                          \
    ASYNC_COPY16(gB0 + _ko + 64 * DIM, _b + 12288);                         \
  }

  // prologue: tile 0 -> buf0, one-time drain.
  STAGE(0, 0);
  VMCNT(0);
  __builtin_amdgcn_s_barrier();

#pragma unroll
  for (int ks = 0; ks < NKS; ks++) {
    const int cur = ks & 1;
    // issue next tile's loads FIRST -- they fly during this iter's reads+MFMA
    if (ks + 1 < NKS) STAGE(cur ^ 1, ks + 1);

    const char* sA = smem + cur * 16384;
    const char* sB = sA + 8192;
    bf16x8 af[4], bfr[4];
#pragma unroll
    for (int i = 0; i < 4; i++)
      af[i] = *reinterpret_cast<const bf16x8*>(sA + (wr + i * 16 + cl) * 64 + kxl);
#pragma unroll
    for (int j = 0; j < 4; j++)
      bfr[j] = *reinterpret_cast<const bf16x8*>(sB + (wc + j * 16 + cl) * 64 + kxl);
#pragma unroll
    for (int i = 0; i < 4; i++)
#pragma unroll
      for (int j = 0; j < 4; j++)
        acc[i][j] = __builtin_amdgcn_mfma_f32_16x16x32_bf16(af[i], bfr[j], acc[i][j], 0, 0, 0);

    // wait only for our own 4 staged loads (issued ~whole iteration ago)
    if (ks + 1 < NKS) VMCNT(0);
    __builtin_amdgcn_s_barrier();
  }
#undef STAGE

  // Epilogue: e = exp(s - C) with diagonal masked.
  // C-frag layout: col = cl, row = q*4 + r (within 16x16 frag (i,j)).
  const bool diagw = (rt == ct) && (wr == wc);
  float psum[4][4];
#pragma unroll
  for (int i = 0; i < 4; i++)
#pragma unroll
    for (int r = 0; r < 4; r++) psum[i][r] = 0.f;
  float colp[4] = {0.f, 0.f, 0.f, 0.f};

#pragma unroll
  for (int i = 0; i < 4; i++)
#pragma unroll
    for (int j = 0; j < 4; j++)
#pragma unroll
      for (int r = 0; r < 4; r++) {
        float e = exp2f(fmaf(acc[i][j][r], LOG2E, -C_LOG2E));
        if (diagw && (i == j) && (cl == q * 4 + r)) e = 0.f;
        psum[i][r] += e;
        colp[j] += e;
      }

  // row sums -> rt rows (reduce across cols: cl lanes)
#pragma unroll
  for (int i = 0; i < 4; i++)
#pragma unroll
    for (int r = 0; r < 4; r++) {
      float v = psum[i][r];
      v += __shfl_xor(v, 1, 64);
      v += __shfl_xor(v, 2, 64);
      v += __shfl_xor(v, 4, 64);
      v += __shfl_xor(v, 8, 64);
      if (cl == 0) atomicAdd(&rowsum[rt * 128 + wr + i * 16 + q * 4 + r], v);
    }

  // col sums -> ct rows (reduce across rows: q lanes), off-diagonal tiles only
  if (rt != ct) {
#pragma unroll
    for (int j = 0; j < 4; j++) {
      float v = colp[j];
      v += __shfl_xor(v, 16, 64);
      v += __shfl_xor(v, 32, 64);
      if (q == 0) atomicAdd(&rowsum[ct * 128 + wc + j * 16 + cl], v);
    }
  }
}

// Single-block finalize: 1024 threads, each handles 8 rows.
__global__ void k_final(const float* __restrict__ rowsum, const float* __restrict__ posbuf,
                        float* __restrict__ out) {
  __shared__ float red[16];
  const int t = threadIdx.x;   // 1024 threads
  float s = 0.f;
#pragma unroll
  for (int it = 0; it < TWO_N / 1024; it++) {
    const int row = it * 1024 + t;
    float v = logf(rowsum[row]);
    if (row < N_ROWS) v -= 2.f * posbuf[row];
    s += v;
  }
#pragma unroll
  for (int off = 32; off > 0; off >>= 1) s += __shfl_down(s, off, 64);
  if ((t & 63) == 0) red[t >> 6] = s;
  __syncthreads();
  if (t == 0) {
    float tot = 0.f;
#pragma unroll
    for (int i = 0; i < 16; i++) tot += red[i];
    out[0] = tot / (float)TWO_N + INV_T;
  }
}

extern "C" void kernel_launch(void* const* d_in, const int* in_sizes, int n_in,
                              void* d_out, int out_size, void* d_ws, size_t ws_size,
                              hipStream_t stream) {
  const float* z1 = (const float*)d_in[0];
  const float* z2 = (const float*)d_in[1];
  float* out = (float*)d_out;
  char* ws = (char*)d_ws;

  __hip_bfloat16* zn = (__hip_bfloat16*)ws;              // 8192*512*2 = 8388608 B
  float* rowsum = (float*)(ws + 8388608);                 // 8192*4 = 32768 B
  float* posbuf = (float*)(ws + 8421376);                 // 4096*4 = 16384 B

  k_prep<<<1024, 256, 0, stream>>>(z1, z2, zn, posbuf, rowsum);
  k_lse<<<2080, 256, 0, stream>>>(zn, rowsum);
  k_final<<<1, 1024, 0, stream>>>(rowsum, posbuf, out);
}